// Round 9
// baseline (212.097 us; speedup 1.0000x reference)
//
#include <hip/hip_runtime.h>
#include <hip/hip_bf16.h>

#define N 8192
#define D 1024
#define MARGIN 1.0f
#define TSTR 132   // epilogue LDS tile stride in u16

typedef __attribute__((ext_vector_type(8))) short bf16x8;
typedef __attribute__((ext_vector_type(4))) float f32x4;
typedef __attribute__((ext_vector_type(8))) _Float16 f16x8;
typedef __attribute__((ext_vector_type(4))) _Float16 f16x4;
typedef __attribute__((ext_vector_type(8))) unsigned short u16x8;

__device__ inline unsigned short f2bf(float x) {
    unsigned u = __float_as_uint(x);
    unsigned r = (u + 0x7FFFu + ((u >> 16) & 1u)) >> 16;  // RNE
    return (unsigned short)r;
}

__device__ inline float h2f(unsigned hb) {
    return (float)__builtin_bit_cast(_Float16, (unsigned short)(hb & 0xFFFFu));
}

// decode linear id -> (a, b) with b >= a over 64x64 upper-tri tile grid
__device__ inline void tri_decode(int l, int& a, int& b) {
    int bb = (int)((sqrtf(8.0f * (float)l + 1.0f) - 1.0f) * 0.5f);
    while ((bb + 1) * (bb + 2) / 2 <= l) ++bb;
    while (bb * (bb + 1) / 2 > l) --bb;
    b = bb;
    a = l - bb * (bb + 1) / 2;
}

// Kernel 0: fp32 -> bf16 copy + per-row sum of squares; first 32 blocks also
// stage cls bytes and init the atomic mining arrays + out.
__global__ __launch_bounds__(256) void prep_kernel(const float* __restrict__ E,
                                                   const int* __restrict__ target,
                                                   unsigned short* __restrict__ Ebf,
                                                   float* __restrict__ sq,
                                                   unsigned char* __restrict__ cls,
                                                   unsigned* __restrict__ P,
                                                   unsigned* __restrict__ Nn,
                                                   unsigned* __restrict__ S,
                                                   float* __restrict__ out) {
    const int r = blockIdx.x;
    const int tid = threadIdx.x;
    if (r < 32) {
        const int idx = r * 256 + tid;
        cls[idx] = (unsigned char)target[idx];
        P[idx] = 0u;
        Nn[idx] = 0xFFFFFFFFu;
        S[idx] = 0xFFFFFFFFu;
        if (idx == 0) out[0] = 0.0f;
    }
    const float4 v = ((const float4*)(E + (size_t)r * D))[tid];
    ushort4 o;
    o.x = f2bf(v.x); o.y = f2bf(v.y); o.z = f2bf(v.z); o.w = f2bf(v.w);
    ((ushort4*)(Ebf + (size_t)r * D))[tid] = o;
    float s = v.x * v.x + v.y * v.y + v.z * v.z + v.w * v.w;
    for (int off = 32; off > 0; off >>= 1) s += __shfl_down(s, off);
    __shared__ float red[4];
    const int lane = tid & 63, wave = tid >> 6;
    if (lane == 0) red[wave] = s;
    __syncthreads();
    if (tid == 0) sq[r] = red[0] + red[1] + red[2] + red[3];
}

// Kernel 1: symmetric D2, upper-triangle-only storage, k-seg swizzled LDS.
// LDS granule p of row r holds global k-seg (p + (r>>1)) & 3  -> fragment
// ds_read_b128s become bank-conflict-free (8 accesses/bank per wave64).
__global__ __launch_bounds__(256) void gemm_kernel(const unsigned short* __restrict__ E,
                                                   const float* __restrict__ sq,
                                                   _Float16* __restrict__ D2h) {
    __shared__ char smem[128 * TSTR * 2];                 // 33792 B
    unsigned short* As = (unsigned short*)smem;           // 8 KB (K-loop)
    unsigned short* Bs = (unsigned short*)(smem + 8192);  // 8 KB (K-loop)
    _Float16* Ts = (_Float16*)smem;                       // 128 x (stride 132) fp16 (epilogue)

    const int tid = threadIdx.x;
    const int lane = tid & 63;
    const int wave = tid >> 6;
    const int wm = wave & 1, wn = wave >> 1;

    int bx, by;
    tri_decode(blockIdx.x, bx, by);
    const int rm = by * 128;
    const int cn = bx * 128;

    const int srow = tid >> 2;
    const int rot_s = (srow >> 1) & 3;
    const int scol = (((tid & 3) + rot_s) & 3) * 8;   // swizzled global k-seg

    const unsigned short* gA = E + (size_t)(rm + srow) * D + scol;
    const unsigned short* gB = E + (size_t)(cn + srow) * D + scol;

    f32x4 acc[4][4] = {};

    const int mr = lane & 15;
    const int kq2 = ((((lane >> 4)) - ((mr >> 1) & 3)) & 3) * 8;  // swizzled read pos

    for (int k0 = 0; k0 < D; k0 += 32) {
        __builtin_amdgcn_global_load_lds(
            (const __attribute__((address_space(1))) unsigned int*)(gA + k0),
            (__attribute__((address_space(3))) unsigned int*)((char*)As + wave * 1024), 16, 0, 0);
        __builtin_amdgcn_global_load_lds(
            (const __attribute__((address_space(1))) unsigned int*)(gA + (size_t)64 * D + k0),
            (__attribute__((address_space(3))) unsigned int*)((char*)As + 4096 + wave * 1024), 16, 0, 0);
        __builtin_amdgcn_global_load_lds(
            (const __attribute__((address_space(1))) unsigned int*)(gB + k0),
            (__attribute__((address_space(3))) unsigned int*)((char*)Bs + wave * 1024), 16, 0, 0);
        __builtin_amdgcn_global_load_lds(
            (const __attribute__((address_space(1))) unsigned int*)(gB + (size_t)64 * D + k0),
            (__attribute__((address_space(3))) unsigned int*)((char*)Bs + 4096 + wave * 1024), 16, 0, 0);
        __syncthreads();

        bf16x8 af[4], bfr[4];
#pragma unroll
        for (int mi = 0; mi < 4; ++mi)
            af[mi] = *(const bf16x8*)(As + (wm * 64 + mi * 16 + mr) * 32 + kq2);
#pragma unroll
        for (int ni = 0; ni < 4; ++ni)
            bfr[ni] = *(const bf16x8*)(Bs + (wn * 64 + ni * 16 + mr) * 32 + kq2);
#pragma unroll
        for (int mi = 0; mi < 4; ++mi)
#pragma unroll
            for (int ni = 0; ni < 4; ++ni)
                acc[mi][ni] = __builtin_amdgcn_mfma_f32_16x16x32_bf16(af[mi], bfr[ni], acc[mi][ni], 0, 0, 0);
        __syncthreads();
    }

    const int crow = (lane >> 4) * 4;
    const int ccol = lane & 15;
    float sqj[4];
#pragma unroll
    for (int ni = 0; ni < 4; ++ni)
        sqj[ni] = sq[cn + wn * 64 + ni * 16 + ccol];
#pragma unroll
    for (int mi = 0; mi < 4; ++mi) {
        const int lrow = wm * 64 + mi * 16 + crow;
        const int i0 = rm + lrow;
        float sqi[4];
#pragma unroll
        for (int r = 0; r < 4; ++r) sqi[r] = sq[i0 + r];
#pragma unroll
        for (int ni = 0; ni < 4; ++ni) {
            const int lcol = wn * 64 + ni * 16 + ccol;
            f16x4 tv;
#pragma unroll
            for (int r = 0; r < 4; ++r) {
                float d2 = fmaxf(sqi[r] + sqj[ni] - 2.0f * acc[mi][ni][r], 0.0f);
                tv[r] = (_Float16)d2;
            }
            *(f16x4*)(Ts + (size_t)lcol * TSTR + lrow) = tv;  // transposed stage
        }
    }
    __syncthreads();
    // coalesced store of transposed tile: global row cn+rt, cols rm..rm+127
#pragma unroll
    for (int it = 0; it < 8; ++it) {
        const int rt = it * 16 + (tid >> 4);
        const int seg = tid & 15;
        f16x4 v0 = *(const f16x4*)(Ts + (size_t)rt * TSTR + seg * 8);
        f16x4 v1 = *(const f16x4*)(Ts + (size_t)rt * TSTR + seg * 8 + 4);
        f16x8 v = __builtin_shufflevector(v0, v1, 0, 1, 2, 3, 4, 5, 6, 7);
        *(f16x8*)(D2h + (size_t)(cn + rt) * N + rm + seg * 8) = v;
    }
}

// Kernel 2: mineA — per-tile hardest-pos (u16 max) / hardest-neg (u16 min) for
// row anchors AND col anchors in one row-major sweep; folds via shuffles and
// commits with device atomicMax/Min (order-independent -> deterministic).
__global__ __launch_bounds__(256) void mineA_kernel(const _Float16* __restrict__ D2h,
                                                    const unsigned char* __restrict__ cls,
                                                    unsigned* __restrict__ P,
                                                    unsigned* __restrict__ Nn) {
    __shared__ unsigned char clsA_l[128], clsB_l[128];
    __shared__ unsigned short colP_l[4][128], colN_l[4][128];
    const int tid = threadIdx.x;
    const int lane = tid & 63, wave = tid >> 6;
    int a, b;
    tri_decode(blockIdx.x, a, b);
    if (tid < 128) clsA_l[tid] = cls[a * 128 + tid];
    else           clsB_l[tid - 128] = cls[b * 128 + (tid - 128)];
    __syncthreads();

    const int cg = tid & 15;   // cols cg*8 .. cg*8+7
    const int rg = tid >> 4;   // rows rg + k*16
    const unsigned long long c8 = *(const unsigned long long*)(clsB_l + cg * 8);
    const unsigned short* g = (const unsigned short*)D2h + (size_t)(a * 128) * N + b * 128 + cg * 8;
    const bool offdiag = (a != b);

    unsigned cp[8], cnn[8];
#pragma unroll
    for (int e = 0; e < 8; ++e) { cp[e] = 0u; cnn[e] = 0xFFFFu; }

#pragma unroll
    for (int k = 0; k < 8; ++k) {
        const int r = k * 16 + rg;
        const unsigned rc = clsA_l[r];
        const u16x8 v = *(const u16x8*)(g + (size_t)r * N);
        unsigned rp = 0u, rn = 0xFFFFu;
#pragma unroll
        for (int e = 0; e < 8; ++e) {
            const unsigned hb = v[e];
            const bool s = (((unsigned)(c8 >> (8 * e)) & 0xFFu) == rc);
            rp = max(rp, s ? hb : 0u);
            rn = min(rn, s ? 0xFFFFu : hb);
            cp[e] = max(cp[e], s ? hb : 0u);
            cnn[e] = min(cnn[e], s ? 0xFFFFu : hb);
        }
#pragma unroll
        for (int m = 1; m < 16; m <<= 1) {
            rp = max(rp, (unsigned)__shfl_xor((int)rp, m));
            rn = min(rn, (unsigned)__shfl_xor((int)rn, m));
        }
        if (cg == 0) {
            atomicMax(&P[a * 128 + r], rp);
            atomicMin(&Nn[a * 128 + r], rn);
        }
    }
    if (offdiag) {
#pragma unroll
        for (int e = 0; e < 8; ++e) {
#pragma unroll
            for (int m = 16; m < 64; m <<= 1) {
                cp[e] = max(cp[e], (unsigned)__shfl_xor((int)cp[e], m));
                cnn[e] = min(cnn[e], (unsigned)__shfl_xor((int)cnn[e], m));
            }
        }
        if (lane < 16) {
#pragma unroll
            for (int e = 0; e < 8; ++e) {
                colP_l[wave][cg * 8 + e] = (unsigned short)cp[e];
                colN_l[wave][cg * 8 + e] = (unsigned short)cnn[e];
            }
        }
        __syncthreads();
        if (tid < 128) {
            const unsigned pm = max(max((unsigned)colP_l[0][tid], (unsigned)colP_l[1][tid]),
                                    max((unsigned)colP_l[2][tid], (unsigned)colP_l[3][tid]));
            const unsigned nm = min(min((unsigned)colN_l[0][tid], (unsigned)colN_l[1][tid]),
                                    min((unsigned)colN_l[2][tid], (unsigned)colN_l[3][tid]));
            atomicMax(&P[b * 128 + tid], pm);
            atomicMin(&Nn[b * 128 + tid], nm);
        }
    }
}

// Kernel 3: mineB — per-tile min{bits > lob(anchor)} for row and col anchors
// (strict > excludes all positives and self; class-free). Same sweep shape.
__global__ __launch_bounds__(256) void mineB_kernel(const _Float16* __restrict__ D2h,
                                                    const unsigned* __restrict__ P,
                                                    unsigned* __restrict__ S) {
    __shared__ unsigned short lobA_l[128], lobB_l[128];
    __shared__ unsigned short colS_l[4][128];
    const int tid = threadIdx.x;
    const int lane = tid & 63, wave = tid >> 6;
    int a, b;
    tri_decode(blockIdx.x, a, b);
    if (tid < 128) lobA_l[tid] = (unsigned short)P[a * 128 + tid];
    else           lobB_l[tid - 128] = (unsigned short)P[b * 128 + (tid - 128)];
    __syncthreads();

    const int cg = tid & 15;
    const int rg = tid >> 4;
    unsigned lb[8];
#pragma unroll
    for (int e = 0; e < 8; ++e) lb[e] = lobB_l[cg * 8 + e];
    const unsigned short* g = (const unsigned short*)D2h + (size_t)(a * 128) * N + b * 128 + cg * 8;
    const bool offdiag = (a != b);

    unsigned sc[8];
#pragma unroll
    for (int e = 0; e < 8; ++e) sc[e] = 0xFFFFu;

#pragma unroll
    for (int k = 0; k < 8; ++k) {
        const int r = k * 16 + rg;
        const unsigned lr = lobA_l[r];
        const u16x8 v = *(const u16x8*)(g + (size_t)r * N);
        unsigned sr = 0xFFFFu;
#pragma unroll
        for (int e = 0; e < 8; ++e) {
            const unsigned hb = v[e];
            sr = min(sr, hb > lr ? hb : 0xFFFFu);
            sc[e] = min(sc[e], hb > lb[e] ? hb : 0xFFFFu);
        }
#pragma unroll
        for (int m = 1; m < 16; m <<= 1)
            sr = min(sr, (unsigned)__shfl_xor((int)sr, m));
        if (cg == 0)
            atomicMin(&S[a * 128 + r], sr);
    }
    if (offdiag) {
#pragma unroll
        for (int e = 0; e < 8; ++e) {
#pragma unroll
            for (int m = 16; m < 64; m <<= 1)
                sc[e] = min(sc[e], (unsigned)__shfl_xor((int)sc[e], m));
        }
        if (lane < 16) {
#pragma unroll
            for (int e = 0; e < 8; ++e)
                colS_l[wave][cg * 8 + e] = (unsigned short)sc[e];
        }
        __syncthreads();
        if (tid < 128) {
            const unsigned sm = min(min((unsigned)colS_l[0][tid], (unsigned)colS_l[1][tid]),
                                    min((unsigned)colS_l[2][tid], (unsigned)colS_l[3][tid]));
            atomicMin(&S[b * 128 + tid], sm);
        }
    }
}

// Kernel 4: foldB — per-anchor loss from values + block-reduced mean (32 atomics).
__global__ __launch_bounds__(256) void foldB_kernel(const unsigned* __restrict__ P,
                                                    const unsigned* __restrict__ Nn,
                                                    const unsigned* __restrict__ S,
                                                    float* __restrict__ out) {
    const int tid = threadIdx.x;
    const int i = blockIdx.x * 256 + tid;
    const float lo = h2f(P[i]);
    const float dp = sqrtf(lo);
    const float hw = dp + MARGIN;
    const float hi = hw * hw;
    const float smv = h2f(S[i]);                   // 0xFFFF -> NaN -> fallback
    const float dn2 = (smv < hi) ? smv : h2f(Nn[i]);
    float loss = fmaxf(dp - sqrtf(dn2) + MARGIN, 0.0f);
    for (int off = 32; off > 0; off >>= 1) loss += __shfl_down(loss, off);
    __shared__ float red[4];
    const int lane = tid & 63, wave = tid >> 6;
    if (lane == 0) red[wave] = loss;
    __syncthreads();
    if (tid == 0)
        atomicAdd(out, (red[0] + red[1] + red[2] + red[3]) * (1.0f / N));
}

extern "C" void kernel_launch(void* const* d_in, const int* in_sizes, int n_in,
                              void* d_out, int out_size, void* d_ws, size_t ws_size,
                              hipStream_t stream) {
    const float* E = (const float*)d_in[0];
    const int* target = (const int*)d_in[1];
    float* out = (float*)d_out;
    char* ws = (char*)d_ws;

    // Workspace layout (~144.3 MB):
    unsigned short* Ebf = (unsigned short*)ws;                          // 16 MB
    float* sq           = (float*)(ws + (size_t)16777216);              // 32 KB
    unsigned char* cls  = (unsigned char*)(ws + (size_t)16809984);      // 8 KB (pad 32K)
    unsigned* P         = (unsigned*)(ws + (size_t)16842752);           // 32 KB
    unsigned* Nn        = (unsigned*)(ws + (size_t)16875520);           // 32 KB
    unsigned* S         = (unsigned*)(ws + (size_t)16908288);           // 32 KB
    _Float16* D2h       = (_Float16*)(ws + (size_t)16941056);           // 128 MB

    prep_kernel<<<N, 256, 0, stream>>>(E, target, Ebf, sq, cls, P, Nn, S, out);
    gemm_kernel<<<2080, 256, 0, stream>>>(Ebf, sq, D2h);       // upper-tri tiles
    mineA_kernel<<<2080, 256, 0, stream>>>(D2h, cls, P, Nn);
    mineB_kernel<<<2080, 256, 0, stream>>>(D2h, P, S);
    foldB_kernel<<<N / 256, 256, 0, stream>>>(P, Nn, S, out);
}